// Round 14
// baseline (396.794 us; speedup 1.0000x reference)
//
#include <hip/hip_runtime.h>
#include <hip/hip_bf16.h>

typedef __bf16 bf16_t;
typedef __bf16 bf16x8 __attribute__((ext_vector_type(8)));
typedef float f32x4 __attribute__((ext_vector_type(4)));

__device__ __forceinline__ unsigned short f32_to_bf16_rn(float f) {
  unsigned u = __float_as_uint(f);
  u += 0x7fffu + ((u >> 16) & 1u);
  return (unsigned short)(u >> 16);
}

__device__ __forceinline__ ushort4 cvt4(float4 v) {
  ushort4 o;
  o.x = f32_to_bf16_rn(v.x);
  o.y = f32_to_bf16_rn(v.y);
  o.z = f32_to_bf16_rn(v.z);
  o.w = f32_to_bf16_rn(v.w);
  return o;
}

__device__ __forceinline__ float gelu_exact(float x) {
  return 0.5f * x * (1.0f + erff(x * 0.7071067811865475f));
}

// ---------------- build compacted index list (deterministic scan) ----------
__global__ void build_idx_kernel(const float* __restrict__ mask1,
                                 const float* __restrict__ mask2,
                                 int* __restrict__ idx, int* __restrict__ meta,
                                 int H, int D) {
  __shared__ int sums[1024];
  const int t = threadIdx.x;
  int flags[8];
  int tot = 0;
#pragma unroll
  for (int u = 0; u < 8; ++u) {
    int j = t * 8 + u;
    int f = (mask1[(long long)j * D] != 0.0f) && (mask2[j] != 0.0f);
    flags[u] = f;
    tot += f;
  }
  sums[t] = tot;
  __syncthreads();
  for (int off = 1; off < 1024; off <<= 1) {
    int v = (t >= off) ? sums[t - off] : 0;
    __syncthreads();
    sums[t] += v;
    __syncthreads();
  }
  int pos = sums[t] - tot;
#pragma unroll
  for (int u = 0; u < 8; ++u) {
    if (flags[u]) idx[pos++] = t * 8 + u;
  }
  if (t == 1023) {
    int count = sums[1023];
    meta[0] = count;
    meta[1] = (count + 127) & ~127;  // kpad: multiple of 128
  }
}

// ============================================================================
// Fragment-tiled layout: matrix [R x K] stored as 16x32-elem tiles of 512
// elems (1KB). tile = (r/16)*NKB + (k/32), NKB = K/32. Within tile, elem
// (fr = r%16, k' = k%32 = g*8+e) at offset g*256B + fr*16B + e*2B — so MFMA
// fragment for lane l is the 16B at byte l*16: ONE contiguous 1KB wave load.
// ============================================================================

// -------- fused prep: x -> xb (tiled)  AND  compact+cast w1 -> w1c (tiled) --
__global__ void prep_kernel(const float* __restrict__ x,
                            const float* __restrict__ w1,
                            const int* __restrict__ idx,
                            const int* __restrict__ meta,
                            unsigned short* __restrict__ xb,
                            unsigned short* __restrict__ w1c, int D) {
  const int nx = 4194304;  // M*D/4 quads
  const int count = meta[0];
  const int kpad = meta[1];
  const int nw1 = kpad << 9;  // kpad * D/4 quads
  for (int i = blockIdx.x * 256 + threadIdx.x; i < nx + nw1; i += 2048 * 256) {
    if (i < nx) {
      int row = i >> 9;
      int d0 = (i & 511) << 2;
      ushort4 o = cvt4(((const float4*)x)[i]);
      *(ushort4*)(xb + (size_t)((row >> 4) * 64 + (d0 >> 5)) * 512 +
                  ((d0 >> 3) & 3) * 128 + (row & 15) * 8 + (d0 & 7)) = o;
    } else {
      int q = i - nx;
      int k = q >> 9;
      int d0 = (q & 511) << 2;
      ushort4 o = {0, 0, 0, 0};
      if (k < count)
        o = cvt4(*(const float4*)(w1 + (long long)idx[k] * D + d0));
      *(ushort4*)(w1c + (size_t)((k >> 4) * 64 + (d0 >> 5)) * 512 +
                  ((d0 >> 3) & 3) * 128 + (k & 15) * 8 + (d0 & 7)) = o;
    }
  }
}

// ====== no-LDS direct-fragment GEMM: 128x64 tile, 4 waves (2x2) =============
// No barriers, no LDS, no staging: every operand fragment is a coalesced 1KB
// wave load from the tiled layout; latency hidden by compiler load pipelining
// (ILP) + 16 waves/CU (TLP). Removes the stage->barrier RTT wall (5400
// cyc/CU) that capped all staged variants at slot*residency ~= RTT.
// EPI==1: gelu -> h written in tiled layout (NKBh) for GEMM2. EPI==0: fp32.
#define POOLG 2048
#define W2BLKS 512

template <int EPI, int DOW2>
__global__ __launch_bounds__(256, 4) void gemm_direct_kernel(
    const bf16_t* __restrict__ A, const bf16_t* __restrict__ B,
    void* __restrict__ Cout, int NKBfix, int Kfix, int ncolFix,
    const int* __restrict__ meta, const float* __restrict__ w2src,
    const int* __restrict__ idx, unsigned short* __restrict__ w2c, int H) {
  if (DOW2 && blockIdx.x >= POOLG) {
    // ---- compact + cast w2 -> w2c in tiled layout (NKB2 = kpad/32) ----
    const int count = meta[0];
    const int kpad = meta[1];
    const int NKB2 = kpad >> 5;
    const int kq = kpad >> 2;  // quads per n-row
    const int nq = 2048 * kq;
    for (int q = (blockIdx.x - POOLG) * 256 + threadIdx.x; q < nq;
         q += W2BLKS * 256) {
      int n = q / kq;
      int k0 = (q - n * kq) << 2;
      ushort4 o = {0, 0, 0, 0};
      const float* src = w2src + (long long)n * H;
#pragma unroll
      for (int u = 0; u < 4; ++u) {
        int k = k0 + u;
        unsigned short v = 0;
        if (k < count) v = f32_to_bf16_rn(src[idx[k]]);
        ((unsigned short*)&o)[u] = v;
      }
      *(ushort4*)(w2c + (size_t)((n >> 4) * NKB2 + (k0 >> 5)) * 512 +
                  ((k0 >> 3) & 3) * 128 + (n & 15) * 8 + (k0 & 7)) = o;
    }
    return;
  }

  const int kpad = meta[1];
  const int K = EPI ? Kfix : kpad;
  const int NKB = K >> 5;
  const int NKBa = EPI ? NKBfix : (kpad >> 5);
  const int NKBb = EPI ? NKBfix : (kpad >> 5);
  const int NKBh = kpad >> 5;
  const int ncol = EPI ? (kpad >> 6) : ncolFix;
  const int ntiles = ncol << 6;  // nrow = 64

  const int tid = threadIdx.x;
  const int l = tid & 63;
  const int w = tid >> 6;
  const int wm = w >> 1;
  const int wn = w & 1;
  const int loff = l * 8;  // elems: lane fragment at byte l*16

  for (int tau = blockIdx.x; tau < ntiles; tau += POOLG) {
    const int row = tau & 63;
    const int colI = tau >> 6;
    const int amb = row * 8 + wm * 4;   // A 16-row block base
    const int bnb = colI * 4 + wn * 2;  // B 16-row block base

    const bf16_t* Ap = A + (size_t)amb * NKBa * 512 + loff;
    const bf16_t* Bp = B + (size_t)bnb * NKBb * 512 + loff;

    f32x4 acc[4][2];
#pragma unroll
    for (int m = 0; m < 4; ++m)
#pragma unroll
      for (int n = 0; n < 2; ++n) acc[m][n] = (f32x4){0.f, 0.f, 0.f, 0.f};

#pragma unroll 2
    for (int kb = 0; kb < NKB; ++kb) {
      bf16x8 a[4], b[2];
#pragma unroll
      for (int m = 0; m < 4; ++m)
        a[m] = *(const bf16x8*)(Ap + ((size_t)m * NKBa + kb) * 512);
#pragma unroll
      for (int n = 0; n < 2; ++n)
        b[n] = *(const bf16x8*)(Bp + ((size_t)n * NKBb + kb) * 512);
#pragma unroll
      for (int m = 0; m < 4; ++m)
#pragma unroll
        for (int n = 0; n < 2; ++n)
          acc[m][n] = __builtin_amdgcn_mfma_f32_16x16x32_bf16(a[m], b[n],
                                                              acc[m][n], 0, 0, 0);
    }

    const int lr = (l >> 4) * 4;  // C/D row base within 16 (+reg r)
    const int lc = l & 15;        // C/D col within 16
    if (EPI == 1) {
      // write h in tiled layout: row block = amb+m, k block = colI*2 + wn,
      // k' within 32 = n*16 + lc -> g = n*2 + (lc>>3), e = lc&7
      unsigned short* hb = (unsigned short*)Cout;
#pragma unroll
      for (int m = 0; m < 4; ++m)
#pragma unroll
        for (int n = 0; n < 2; ++n) {
          unsigned short* hp =
              hb + (size_t)((amb + m) * NKBh + colI * 2 + wn) * 512 +
              (n * 2 + (lc >> 3)) * 128 + (lc & 7);
#pragma unroll
          for (int r = 0; r < 4; ++r)
            hp[(lr + r) * 8] = f32_to_bf16_rn(gelu_exact(acc[m][n][r]));
        }
    } else {
      float* o = (float*)Cout;
      const long long r0 = (long long)row * 128 + wm * 64;
      const int c0 = colI * 64 + wn * 32;
#pragma unroll
      for (int m = 0; m < 4; ++m)
#pragma unroll
        for (int n = 0; n < 2; ++n)
#pragma unroll
          for (int r = 0; r < 4; ++r)
            o[(r0 + m * 16 + lr + r) * 2048 + c0 + n * 16 + lc] =
                acc[m][n][r];
    }
  }
}

extern "C" void kernel_launch(void* const* d_in, const int* in_sizes, int n_in,
                              void* d_out, int out_size, void* d_ws,
                              size_t ws_size, hipStream_t stream) {
  const float* x = (const float*)d_in[0];
  const float* w1 = (const float*)d_in[1];
  const float* w2 = (const float*)d_in[2];
  const float* mask1 = (const float*)d_in[3];
  const float* mask2 = (const float*)d_in[4];
  float* out = (float*)d_out;

  const int D = 2048, H = 8192, M = 8192;
  const int KP = 4096;

  char* ws = (char*)d_ws;
  unsigned short* xb = (unsigned short*)ws;          // M*D (tiled)
  unsigned short* w1c = xb + (size_t)M * D;          // KP*D (tiled)
  unsigned short* w2c = w1c + (size_t)KP * D;        // D*KP (tiled)
  unsigned short* hb = w2c + (size_t)D * KP;         // M*KP (tiled)
  int* idx = (int*)(hb + (size_t)M * KP);
  int* meta = idx + KP;

  build_idx_kernel<<<1, 1024, 0, stream>>>(mask1, mask2, idx, meta, H, D);

  // fused: x -> xb tiled, compact+cast w1 -> w1c tiled
  prep_kernel<<<2048, 256, 0, stream>>>(x, w1, idx, meta, xb, w1c, D);

  // GEMM1 (+ w2 compaction on 512 extra blocks):
  // h = gelu(x @ w1c^T), M=8192, N=kpad (device), K=2048. NKB(A,B) = 64.
  gemm_direct_kernel<1, 1><<<POOLG + W2BLKS, 256, 0, stream>>>(
      (const bf16_t*)xb, (const bf16_t*)w1c, hb, 64, D, 0, meta, w2, idx, w2c,
      H);

  // GEMM2: out = h @ w2c^T, M=8192, N=2048, K=kpad (device). NKB dynamic.
  gemm_direct_kernel<0, 0><<<POOLG, 256, 0, stream>>>(
      (const bf16_t*)hb, (const bf16_t*)w2c, out, 0, 0, 32, meta, nullptr,
      nullptr, nullptr, H);
}

// Round 15
// 239.373 us; speedup vs baseline: 1.6576x; 1.6576x over previous
//
#include <hip/hip_runtime.h>
#include <hip/hip_bf16.h>

typedef __bf16 bf16_t;
typedef __bf16 bf16x8 __attribute__((ext_vector_type(8)));
typedef float f32x4 __attribute__((ext_vector_type(4)));

__device__ __forceinline__ unsigned short f32_to_bf16_rn(float f) {
  unsigned u = __float_as_uint(f);
  u += 0x7fffu + ((u >> 16) & 1u);
  return (unsigned short)(u >> 16);
}

__device__ __forceinline__ ushort4 cvt4(float4 v) {
  ushort4 o;
  o.x = f32_to_bf16_rn(v.x);
  o.y = f32_to_bf16_rn(v.y);
  o.z = f32_to_bf16_rn(v.z);
  o.w = f32_to_bf16_rn(v.w);
  return o;
}

__device__ __forceinline__ float gelu_exact(float x) {
  return 0.5f * x * (1.0f + erff(x * 0.7071067811865475f));
}

#define GLDS16(g, l)                                                          \
  __builtin_amdgcn_global_load_lds(                                           \
      (const __attribute__((address_space(1))) void*)(g),                     \
      (__attribute__((address_space(3))) void*)(l), 16, 0, 0)

// ---------------- build compacted index list (deterministic scan) ----------
__global__ void build_idx_kernel(const float* __restrict__ mask1,
                                 const float* __restrict__ mask2,
                                 int* __restrict__ idx, int* __restrict__ meta,
                                 int H, int D) {
  __shared__ int sums[1024];
  const int t = threadIdx.x;
  int flags[8];
  int tot = 0;
#pragma unroll
  for (int u = 0; u < 8; ++u) {
    int j = t * 8 + u;
    int f = (mask1[(long long)j * D] != 0.0f) && (mask2[j] != 0.0f);
    flags[u] = f;
    tot += f;
  }
  sums[t] = tot;
  __syncthreads();
  for (int off = 1; off < 1024; off <<= 1) {
    int v = (t >= off) ? sums[t - off] : 0;
    __syncthreads();
    sums[t] += v;
    __syncthreads();
  }
  int pos = sums[t] - tot;
#pragma unroll
  for (int u = 0; u < 8; ++u) {
    if (flags[u]) idx[pos++] = t * 8 + u;
  }
  if (t == 1023) {
    int count = sums[1023];
    meta[0] = count;
    meta[1] = (count + 127) & ~127;  // kpad: multiple of 128
  }
}

// -------- fused prep: cast x -> bf16  AND  compact+cast w1 rows ------------
__global__ void prep_kernel(const float* __restrict__ x,
                            const float* __restrict__ w1,
                            const int* __restrict__ idx,
                            const int* __restrict__ meta,
                            unsigned short* __restrict__ xb,
                            unsigned short* __restrict__ w1c, int D) {
  const int nx = 4194304;  // M*D/4 quads
  const int count = meta[0];
  const int kpad = meta[1];
  const int nw1 = kpad << 9;  // kpad * D/4 quads
  for (int i = blockIdx.x * 256 + threadIdx.x; i < nx + nw1; i += 2048 * 256) {
    if (i < nx) {
      ((ushort4*)xb)[i] = cvt4(((const float4*)x)[i]);
    } else {
      int q = i - nx;
      int k = q >> 9;
      int d4 = (q & 511) << 2;
      ushort4 o = {0, 0, 0, 0};
      if (k < count)
        o = cvt4(*(const float4*)(w1 + (long long)idx[k] * D + d4));
      *(ushort4*)(w1c + (long long)k * D + d4) = o;
    }
  }
}

// ====== 128x128 tile, BK=64 pool GEMM + circular-K phase stagger ============
// R12's proven kernel (0 bank conflicts, 100us/GEMM) + de-convoy: co-resident
// blocks (bid, bid+256, bid+512, bid+768 share a CU) start the K-loop at
// offsets {0, NT/4, NT/2, 3NT/4} (wrap-around; pure summation reorder,
// deterministic). This staggers their stage/barrier phases so one block's
// MFMA covers another's staging RTT — queue depth without extra blocks.
// DOW2: GEMM1's launch carries 512 extra blocks compacting w2 (only read by
// GEMM2, the next kernel).
#define POOLG 2048
#define W2BLKS 512

template <int EPI, int DOW2>
__global__ __launch_bounds__(256, 4) void gemm_pool_kernel(
    const bf16_t* __restrict__ A, const bf16_t* __restrict__ B,
    void* __restrict__ Cout, long long ldA, long long ldB, long long ldC,
    int Kfix, int ncolFix, const int* __restrict__ meta,
    const float* __restrict__ w2src, const int* __restrict__ idx,
    unsigned short* __restrict__ w2c, int H) {
  if (DOW2 && blockIdx.x >= POOLG) {
    // ---- compact + cast w2 cols (ld 4096), grid-strided over 512 blocks ----
    const int nq = 2097152;  // D*KP/4
    const int count = meta[0];
    for (int q = (blockIdx.x - POOLG) * 256 + threadIdx.x; q < nq;
         q += W2BLKS * 256) {
      int n = q >> 10;
      int k4 = (q & 1023) << 2;
      ushort4 o = {0, 0, 0, 0};
      const float* src = w2src + (long long)n * H;
#pragma unroll
      for (int u = 0; u < 4; ++u) {
        int k = k4 + u;
        unsigned short v = 0;
        if (k < count) v = f32_to_bf16_rn(src[idx[k]]);
        ((unsigned short*)&o)[u] = v;
      }
      *(ushort4*)(w2c + (long long)n * 4096 + k4) = o;
    }
    return;
  }

  const int kpad = meta[1];
  const int K = (EPI == 0) ? kpad : Kfix;               // GEMM2: K dynamic
  const int ncol = (EPI == 1) ? (kpad >> 7) : ncolFix;  // GEMM1: cols dynamic
  const int ntiles = ncol << 6;                         // nrow = 64
  const int NT = K >> 6;
  // circular-K start phase: 4 groups of 256 blocks -> 4 phases per CU
  const int phase = ((blockIdx.x >> 8) & 3) * (NT >> 2);

  __shared__ bf16_t As[128 * 64];  // 16 KB
  __shared__ bf16_t Bs[128 * 64];  // 16 KB

  const int tid = threadIdx.x;
  const int l = tid & 63;
  const int w = tid >> 6;
  const int wm = w >> 1;  // 0..1 : 64-row half
  const int wn = w & 1;   // 0..1 : 64-col half

  // staging: thread -> row tid>>3 within 32-row pass, phys granule tid&7;
  // source column pre-swizzled by row&7 (pass stride 32 preserves row&7).
  const int srow = tid >> 3;                          // 0..31
  const int sg = ((tid & 7) ^ ((tid >> 3) & 7)) * 8;  // src col elems

  const int fr = l & 15;
  const int gA = (l >> 4) ^ (l & 7);

  for (int tau = blockIdx.x; tau < ntiles; tau += POOLG) {
    const int row = tau & 63;
    const int col = tau >> 6;
    const long long brow = (long long)row * 128;
    const long long bcol = (long long)col * 128;

    const bf16_t* Ag = A + (brow + srow) * ldA + sg;
    const bf16_t* Bg = B + (bcol + srow) * ldB + sg;

    f32x4 acc[4][4];
#pragma unroll
    for (int m = 0; m < 4; ++m)
#pragma unroll
      for (int n = 0; n < 4; ++n) acc[m][n] = (f32x4){0.f, 0.f, 0.f, 0.f};

    for (int it = 0; it < NT; ++it) {
      int t = it + phase;
      if (t >= NT) t -= NT;
      const int k0 = t << 6;
      GLDS16(Ag + k0, &As[tid * 8]);
      GLDS16(Ag + 32 * ldA + k0, &As[2048 + tid * 8]);
      GLDS16(Ag + 64 * ldA + k0, &As[4096 + tid * 8]);
      GLDS16(Ag + 96 * ldA + k0, &As[6144 + tid * 8]);
      GLDS16(Bg + k0, &Bs[tid * 8]);
      GLDS16(Bg + 32 * ldB + k0, &Bs[2048 + tid * 8]);
      GLDS16(Bg + 64 * ldB + k0, &Bs[4096 + tid * 8]);
      GLDS16(Bg + 96 * ldB + k0, &Bs[6144 + tid * 8]);
      __syncthreads();
#pragma unroll
      for (int kk = 0; kk < 2; ++kk) {
        const int gp = (gA ^ (kk * 4)) * 8;
        bf16x8 af[4], bfr[4];
#pragma unroll
        for (int m = 0; m < 4; ++m)
          af[m] = *(const bf16x8*)(&As[(wm * 64 + m * 16 + fr) * 64 + gp]);
#pragma unroll
        for (int n = 0; n < 4; ++n)
          bfr[n] = *(const bf16x8*)(&Bs[(wn * 64 + n * 16 + fr) * 64 + gp]);
#pragma unroll
        for (int m = 0; m < 4; ++m)
#pragma unroll
          for (int n = 0; n < 4; ++n)
            acc[m][n] = __builtin_amdgcn_mfma_f32_16x16x32_bf16(
                af[m], bfr[n], acc[m][n], 0, 0, 0);
      }
      __syncthreads();
    }

    const int orow = wm * 64 + (l >> 4) * 4;
    const int ocol = wn * 64 + fr;
#pragma unroll
    for (int m = 0; m < 4; ++m)
#pragma unroll
      for (int n = 0; n < 4; ++n)
#pragma unroll
        for (int r = 0; r < 4; ++r) {
          long long rr = brow + orow + m * 16 + r;
          long long cc = bcol + ocol + n * 16;
          float v = acc[m][n][r];
          if (EPI == 1) {
            ((unsigned short*)Cout)[rr * ldC + cc] =
                f32_to_bf16_rn(gelu_exact(v));
          } else {
            ((float*)Cout)[rr * ldC + cc] = v;
          }
        }
  }
}

extern "C" void kernel_launch(void* const* d_in, const int* in_sizes, int n_in,
                              void* d_out, int out_size, void* d_ws,
                              size_t ws_size, hipStream_t stream) {
  const float* x = (const float*)d_in[0];
  const float* w1 = (const float*)d_in[1];
  const float* w2 = (const float*)d_in[2];
  const float* mask1 = (const float*)d_in[3];
  const float* mask2 = (const float*)d_in[4];
  float* out = (float*)d_out;

  const int D = 2048, H = 8192, M = 8192;
  const int KP = 4096;

  char* ws = (char*)d_ws;
  unsigned short* xb = (unsigned short*)ws;
  unsigned short* w1c = xb + (size_t)M * D;
  unsigned short* w2c = w1c + (size_t)KP * D;
  unsigned short* hb = w2c + (size_t)D * KP;
  int* idx = (int*)(hb + (size_t)M * KP);
  int* meta = idx + KP;

  build_idx_kernel<<<1, 1024, 0, stream>>>(mask1, mask2, idx, meta, H, D);

  // fused: cast x -> bf16, compact+cast w1
  prep_kernel<<<2048, 256, 0, stream>>>(x, w1, idx, meta, xb, w1c, D);

  // GEMM1 (+ compact_w2 on 512 extra blocks):
  // h[:, 0:kpad] = gelu(x @ w1c^T). K=2048 fixed; ncol = kpad/128 (device)
  gemm_pool_kernel<1, 1><<<POOLG + W2BLKS, 256, 0, stream>>>(
      (const bf16_t*)xb, (const bf16_t*)w1c, hb, (long long)D, (long long)D,
      (long long)KP, D, 0, meta, w2, idx, w2c, H);

  // GEMM2: out = h @ w2c^T. K = kpad (device); ncol = 2048/128 = 16 fixed
  gemm_pool_kernel<0, 0><<<1024, 256, 0, stream>>>(
      (const bf16_t*)hb, (const bf16_t*)w2c, out, (long long)KP,
      (long long)KP, (long long)D, 0, 16, meta, nullptr, nullptr, nullptr, H);
}